// Round 7
// baseline (147.265 us; speedup 1.0000x reference)
//
#include <hip/hip_runtime.h>
#include <hip/hip_bf16.h>
#include <stdint.h>

// BERT self-attention fwd: B=2, S=2048, D=768, H=12, W=64. f32 in/out, bf16 MFMA inside.
// Stage 1: cvt x,Wq,Wk,Wv -> bf16 (one kernel).
// Stage 2: QKV projection GEMM, BK=32, 3-buf LDS, depth-2 prefetch, 2 barriers/iter.
// Stage 3: flash attention, 32x32 MFMA, no-max softmax, swapped QK^T, in-register P via
//   cvt_pk + permlane32_swap, row-sum via MFMA-with-ones. K via LDS (4 bufs, depth-2,
//   ONE barrier/iter — 4 bufs make single-barrier depth-2 race-free); V direct
//   global->VGPR issued at body top (L2 latency hidden under QK+softmax). 33.3KB LDS +
//   launch_bounds(256,4) -> 4 blocks/CU, 16 waves/CU.

typedef __attribute__((ext_vector_type(8))) short bf16x8;    // 8 bf16 = 4 VGPR (MFMA A/B frag)
typedef __attribute__((ext_vector_type(4))) float f32x4;     // 16x16 MFMA C/D frag
typedef __attribute__((ext_vector_type(16))) float f32x16;   // 32x32 MFMA C/D frag
typedef __attribute__((ext_vector_type(8))) unsigned short u16x8;

#define MFMA16(a, b, c) __builtin_amdgcn_mfma_f32_16x16x32_bf16((a), (b), (c), 0, 0, 0)
#define MFMA32(a, b, c) __builtin_amdgcn_mfma_f32_32x32x16_bf16((a), (b), (c), 0, 0, 0)
#define SWZ(row, colb) ((colb) ^ (((row) & 7) << 4))  // 128B-row swizzle (epilogue only)

union U32x4BF {
  unsigned u[4];
  bf16x8 v;
};

__device__ __forceinline__ void gl_lds16(const void* g, void* l) {
  __builtin_amdgcn_global_load_lds(
      (__attribute__((address_space(1))) void*)const_cast<void*>(g),
      (__attribute__((address_space(3))) void*)l, 16, 0, 0);
}

__device__ __forceinline__ unsigned short f2bf(float x) {  // RNE f32->bf16
  unsigned int v = __float_as_uint(x);
  return (unsigned short)((v + 0x7fffu + ((v >> 16) & 1u)) >> 16);
}

// ---------------- Stage 1: f32 -> bf16 convert ----------------
__global__ __launch_bounds__(256) void cvt_all(
    const float* __restrict__ x, const float* __restrict__ wq,
    const float* __restrict__ wk, const float* __restrict__ wv,
    unsigned short* __restrict__ xb, unsigned short* __restrict__ wb) {
  int i = blockIdx.x * 256 + threadIdx.x;  // group-of-8 index; total 614400
  const float* s;
  unsigned short* d;
  int off;
  if (i < 393216)      { s = x;  d = xb;            off = i; }
  else if (i < 466944) { s = wq; d = wb;            off = i - 393216; }
  else if (i < 540672) { s = wk; d = wb + 589824;   off = i - 466944; }
  else                 { s = wv; d = wb + 1179648;  off = i - 540672; }
  const float4* sp = (const float4*)s + (size_t)off * 2;
  float4 a = sp[0], b2 = sp[1];
  u16x8 o;
  o[0] = f2bf(a.x); o[1] = f2bf(a.y); o[2] = f2bf(a.z); o[3] = f2bf(a.w);
  o[4] = f2bf(b2.x); o[5] = f2bf(b2.y); o[6] = f2bf(b2.z); o[7] = f2bf(b2.w);
  *((u16x8*)d + off) = o;
}

// ---------------- Stage 2: fused QKV projection (BK=32, 3-buf, depth-2) ----------------
__global__ __launch_bounds__(256) void proj_gemm(
    const unsigned short* __restrict__ xb, const unsigned short* __restrict__ wb,
    const float* __restrict__ bq, const float* __restrict__ bk, const float* __restrict__ bv,
    unsigned short* __restrict__ qw, unsigned short* __restrict__ kw,
    unsigned short* __restrict__ vw) {
  __shared__ __align__(16) char psmem[49152];  // 3 bufs x (A 8KB | B 8KB)
  const int t = threadIdx.x, lane = t & 63, wave = t >> 6;
  const int lo = lane & 15, hi = lane >> 4;  // hi in 0..3
  const int wr = wave >> 1, wc = wave & 1;   // 2x2 waves, 64x64 each
  const int mbase = blockIdx.x * 128;
  const int wsel = blockIdx.y / 6;
  const int nbase = (blockIdx.y % 6) * 128;
  const char* xc = (const char*)xb;
  const char* wmc = (const char*)(wb + (size_t)wsel * 589824);

  const int pp0 = t * 16, pp1 = t * 16 + 4096;
  const int ar0 = pp0 >> 7, ac0 = (pp0 & 127) ^ ((ar0 & 7) << 4);
  const int am0 = ((ac0 >> 6) << 6) + ar0, ak0 = ac0 & 63;
  const int ar1 = pp1 >> 7, ac1 = (pp1 & 127) ^ ((ar1 & 7) << 4);
  const int am1 = ((ac1 >> 6) << 6) + ar1, ak1 = ac1 & 63;

  const char* xa0 = xc + (size_t)(mbase + am0) * 1536 + ak0;
  const char* xa1 = xc + (size_t)(mbase + am1) * 1536 + ak1;
  const char* wa0 = wmc + (size_t)(nbase + am0) * 1536 + ak0;
  const char* wa1 = wmc + (size_t)(nbase + am1) * 1536 + ak1;

#define PSTAGE(BUF)                              \
  do {                                           \
    char* lb = psmem + (BUF) * 16384;            \
    gl_lds16(xa0, lb + pp0);                     \
    gl_lds16(xa1, lb + pp1);                     \
    gl_lds16(wa0, lb + 8192 + pp0);              \
    gl_lds16(wa1, lb + 8192 + pp1);              \
    xa0 += 64; xa1 += 64; wa0 += 64; wa1 += 64;  \
  } while (0)

  f32x4 acc[4][4];
#pragma unroll
  for (int i = 0; i < 4; i++)
#pragma unroll
    for (int j = 0; j < 4; j++) acc[i][j] = (f32x4){0.f, 0.f, 0.f, 0.f};

  const int axor = (lo & 7) << 4;
  PSTAGE(0);
  PSTAGE(1);
  int cur = 0, sb = 2;
#pragma unroll 1
  for (int it = 0; it < 24; ++it) {
    if (it < 22) {
      PSTAGE(sb);
      asm volatile("s_waitcnt vmcnt(8)" ::: "memory");
    } else if (it == 22) {
      asm volatile("s_waitcnt vmcnt(4)" ::: "memory");
    } else {
      asm volatile("s_waitcnt vmcnt(0)" ::: "memory");
    }
    __builtin_amdgcn_s_barrier();
    const char* lA = psmem + cur * 16384;
    const char* lB = lA + 8192;

    bf16x8 af[4], bf[4];
#pragma unroll
    for (int mf = 0; mf < 4; mf++)
      af[mf] = *(const bf16x8*)(lA + (mf * 16 + lo) * 128 + ((wr * 64 + hi * 16) ^ axor));
#pragma unroll
    for (int nf = 0; nf < 4; nf++)
      bf[nf] = *(const bf16x8*)(lB + (nf * 16 + lo) * 128 + ((wc * 64 + hi * 16) ^ axor));

    __builtin_amdgcn_s_setprio(1);
    if (wsel == 2) {  // V: operand-swapped -> acc holds C^T (rows=n, cols=m)
#pragma unroll
      for (int mf = 0; mf < 4; mf++)
#pragma unroll
        for (int nf = 0; nf < 4; nf++) acc[mf][nf] = MFMA16(bf[nf], af[mf], acc[mf][nf]);
    } else {
#pragma unroll
      for (int mf = 0; mf < 4; mf++)
#pragma unroll
        for (int nf = 0; nf < 4; nf++) acc[mf][nf] = MFMA16(af[mf], bf[nf], acc[mf][nf]);
    }
    __builtin_amdgcn_s_setprio(0);
    __builtin_amdgcn_s_barrier();  // trailing barrier: depth-2 with 3 bufs race-free
    cur = (cur == 2) ? 0 : cur + 1;
    sb = (sb == 2) ? 0 : sb + 1;
  }
#undef PSTAGE

  const float QSCALE = 0.125f * 1.44269504089f;  // fold 1/sqrt(64) * log2(e)
  if (wsel == 2) {
#pragma unroll
    for (int nf = 0; nf < 4; nf++) {
#pragma unroll
      for (int mf = 0; mf < 4; mf++) {
#pragma unroll
        for (int r = 0; r < 4; r++) {
          int n = nbase + wc * 64 + nf * 16 + hi * 4 + r;
          int m = mbase + wr * 64 + mf * 16 + lo;
          int b_ = m >> 11, s = m & 2047;
          int h = n >> 6, wcol = n & 63;
          float val = acc[mf][nf][r] + bv[n];
          vw[(((size_t)b_ * 12 + h) * 64 + wcol) * 2048 + s] = f2bf(val);
        }
      }
    }
  } else {
    const float* bias = (wsel == 0) ? bq : bk;
#pragma unroll
    for (int nf = 0; nf < 4; nf++) {
      int n = nbase + wc * 64 + nf * 16 + lo;
      float bv_ = bias[n];
      int h = n >> 6, wcol = n & 63;
#pragma unroll
      for (int mf = 0; mf < 4; mf++) {
#pragma unroll
        for (int r = 0; r < 4; r++) {
          int m = mbase + wr * 64 + mf * 16 + hi * 4 + r;
          int b_ = m >> 11, s = m & 2047;
          float val = acc[mf][nf][r] + bv_;
          size_t bhh = (size_t)b_ * 12 + h;
          if (wsel == 0)
            qw[(bhh * 2048 + s) * 64 + wcol] = f2bf(val * QSCALE);
          else
            kw[(bhh * 2048 + s) * 64 + wcol] = f2bf(val);
        }
      }
    }
  }
}

// ---------------- Stage 3: flash attention ----------------
// grid (32, 24), block 256 = 4 waves (wq q-half x wk key-half). KT=64 keys/iter, 32 iters.
// K tile [16][512B] LDS (4 bufs, depth-2, single barrier/iter); V direct global->VGPR.
// vmcnt ledger (per iter): entry in-flight = K(it+1):2. Issue V(it):4, K-stage(it+2):2 ->
//   top vmcnt(8) free (K(it) forced by prev iter's vmcnt(2)); pre-PV vmcnt(2): V done,
//   K(it+2) stays in flight. 4 bufs => writer (it+2)&3 never aliases readers it&3/(it-1)&3.
__global__ __launch_bounds__(256, 4) void attn_kernel(
    const unsigned short* __restrict__ qw, const unsigned short* __restrict__ kw,
    const unsigned short* __restrict__ vw, const int* __restrict__ mask,
    float* __restrict__ out) {
  // [0,32768): 4 K bufs (8KB) | [32768,33024) ballots | [33024,33280) lsum f32[64]
  __shared__ __align__(16) char smem[33280];
  const int t = threadIdx.x, lane = t & 63, wave = t >> 6;
  const int wq = wave >> 1, wk = wave & 1;
  const int l31 = lane & 31, hl = lane >> 5;
  const int qb = blockIdx.x, bh = blockIdx.y;
  const int b = bh / 12, hh = bh - b * 12;

  // bit-pack mask: thread t packs keys [t*8, t*8+8) -> ballot bytes
  {
    const int* mb = mask + (size_t)b * 2048 + t * 8;
    int4 a0 = *(const int4*)mb;
    int4 a1 = *(const int4*)(mb + 4);
    unsigned by = (unsigned)(a0.x != 0) | ((unsigned)(a0.y != 0) << 1) |
                  ((unsigned)(a0.z != 0) << 2) | ((unsigned)(a0.w != 0) << 3) |
                  ((unsigned)(a1.x != 0) << 4) | ((unsigned)(a1.y != 0) << 5) |
                  ((unsigned)(a1.z != 0) << 6) | ((unsigned)(a1.w != 0) << 7);
    smem[32768 + t] = (char)by;
  }

  // Q B-frags in registers: lane holds Q[q = l31 of wq-half][d = 16s + 8hl + j]
  bf16x8 qv[4];
  {
    int qrow = qb * 64 + wq * 32 + l31;
    const char* qp = (const char*)qw + ((size_t)bh * 2048 + qrow) * 128 + hl * 16;
#pragma unroll
    for (int s = 0; s < 4; s++) qv[s] = *(const bf16x8*)(qp + s * 32);
  }

  // K staging maps: linear p -> (key, byte-within-row), pre-swizzled source
  const int p0 = t * 16, p1 = t * 16 + 4096;
  const int r0 = p0 >> 9, c0 = (p0 >> 7) & 3, o0 = (p0 & 127) ^ ((r0 & 7) << 4);
  const int r1 = p1 >> 9, c1 = (p1 >> 7) & 3, o1 = (p1 & 127) ^ ((r1 & 7) << 4);
  const char* kp0 = (const char*)kw + (size_t)bh * 262144 + (c0 * 16 + r0) * 128 + o0;
  const char* kp1 = (const char*)kw + (size_t)bh * 262144 + (c1 * 16 + r1) * 128 + o1;

  // V direct-global pointers: frag (wh, sp) at vptr(wh) + sp*32; bump +128/iter
  const char* vptr0 = (const char*)vw + (size_t)bh * 262144 + (size_t)l31 * 4096 +
                      wk * 64 + hl * 16;                   // wh=0 rows l31
  const char* vptr1 = vptr0 + (size_t)32 * 4096;           // wh=1 rows 32+l31

#define STAGEP(BUF_)                       \
  do {                                     \
    char* kb_ = smem + (BUF_) * 8192;      \
    gl_lds16(kp0, kb_ + p0);               \
    gl_lds16(kp1, kb_ + p1);               \
    kp0 += 8192; kp1 += 8192;              \
  } while (0)

  f32x16 oacc[2], lsacc;
#pragma unroll
  for (int wh = 0; wh < 2; wh++)
#pragma unroll
    for (int g = 0; g < 16; g++) oacc[wh][g] = 0.f;
#pragma unroll
  for (int g = 0; g < 16; g++) lsacc[g] = 0.f;
  U32x4BF onesv;
  onesv.u[0] = onesv.u[1] = onesv.u[2] = onesv.u[3] = 0x3F803F80u;  // 8x bf16 1.0

  const int kbl = (l31 & 15) * 512 + (wk * 2 + (l31 >> 4)) * 128;  // K frag row part
  const int rxor = (l31 & 7) << 4;
  const int hl16 = hl * 16;

  asm volatile("s_waitcnt lgkmcnt(0)" ::: "memory");  // ballot byte visible
  STAGEP(0);
  STAGEP(1);
  __syncthreads();  // publish ballots (K bufs gated by loop vmcnt+barrier)

// One KV-tile: V loads -> K-stage(it+2) -> vmcnt(top) -> barrier -> QK^T -> mask -> exp2
//   -> pack/permlane -> rowsum-MFMA -> vmcnt(pv) -> PV. Single barrier per iter.
#define BODY(IT_, BUF_, DOSTAGE_, SBUF_, VMTOP_, VMPV_)                                \
  {                                                                                    \
    bf16x8 vf00 = *(const bf16x8*)(vptr0);                                             \
    bf16x8 vf01 = *(const bf16x8*)(vptr0 + 32);                                        \
    bf16x8 vf10 = *(const bf16x8*)(vptr1);                                             \
    bf16x8 vf11 = *(const bf16x8*)(vptr1 + 32);                                        \
    vptr0 += 128; vptr1 += 128;                                                        \
    asm volatile("" ::: "memory"); /* keep V loads issued before K staging */          \
    if (DOSTAGE_) STAGEP(SBUF_);                                                       \
    asm volatile("s_waitcnt vmcnt(" #VMTOP_ ")" ::: "memory");                         \
    __builtin_amdgcn_s_barrier();                                                      \
    const char* lKc_ = smem + (BUF_) * 8192;                                           \
    f32x16 sc_;                                                                        \
    _Pragma("unroll") for (int g = 0; g < 16; g++) sc_[g] = 0.f;                       \
    __builtin_amdgcn_s_setprio(1);                                                     \
    _Pragma("unroll") for (int s = 0; s < 4; s++) {                                    \
      bf16x8 kf_ = *(const bf16x8*)(lKc_ + kbl + ((s * 32 + hl16) ^ rxor));            \
      sc_ = MFMA32(kf_, qv[s], sc_);                                                   \
    }                                                                                  \
    __builtin_amdgcn_s_setprio(0);                                                     \
    unsigned long long bal_ = *(const unsigned long long*)(smem + 32768 + (IT_) * 8);  \
    if (bal_ != ~0ull) {                                                               \
      _Pragma("unroll") for (int g = 0; g < 16; g++) {                                 \
        int key_ = wk * 32 + 4 * hl + (g & 3) + 8 * (g >> 2);                          \
        if (!((bal_ >> key_) & 1)) sc_[g] = -30000.f;                                  \
      }                                                                                \
    }                                                                                  \
    float e_[16];                                                                      \
    _Pragma("unroll") for (int g = 0; g < 16; g++)                                     \
        asm("v_exp_f32 %0, %1" : "=v"(e_[g]) : "v"(sc_[g]));                           \
    unsigned pk_[4][2];                                                                \
    _Pragma("unroll") for (int m = 0; m < 4; m++) {                                    \
      asm("v_cvt_pk_bf16_f32 %0, %1, %2"                                               \
          : "=v"(pk_[m][0]) : "v"(e_[4 * m]), "v"(e_[4 * m + 1]));                     \
      asm("v_cvt_pk_bf16_f32 %0, %1, %2"                                               \
          : "=v"(pk_[m][1]) : "v"(e_[4 * m + 2]), "v"(e_[4 * m + 3]));                 \
    }                                                                                  \
    U32x4BF apv_[2];                                                                   \
    _Pragma("unroll") for (int sp = 0; sp < 2; sp++)                                   \
        _Pragma("unroll") for (int cp = 0; cp < 2; cp++) {                             \
      unsigned xx_ = pk_[2 * sp][cp], yy_ = pk_[2 * sp + 1][cp];                       \
      asm("v_permlane32_swap_b32 %0, %1" : "+v"(xx_), "+v"(yy_));                      \
      apv_[sp].u[cp] = xx_;                                                            \
      apv_[sp].u[2 + cp] = yy_;                                                        \
    }                                                                                  \
    __builtin_amdgcn_s_setprio(1);                                                     \
    lsacc = MFMA32(apv_[0].v, onesv.v, lsacc);                                         \
    lsacc = MFMA32(apv_[1].v, onesv.v, lsacc);                                         \
    __builtin_amdgcn_s_setprio(0);                                                     \
    asm volatile("s_waitcnt vmcnt(" #VMPV_ ")" ::: "memory");                          \
    __builtin_amdgcn_s_setprio(1);                                                     \
    oacc[0] = MFMA32(apv_[0].v, vf00, oacc[0]);                                        \
    oacc[0] = MFMA32(apv_[1].v, vf01, oacc[0]);                                        \
    oacc[1] = MFMA32(apv_[0].v, vf10, oacc[1]);                                        \
    oacc[1] = MFMA32(apv_[1].v, vf11, oacc[1]);                                        \
    __builtin_amdgcn_s_setprio(0);                                                     \
  }

#pragma unroll 1
  for (int itb = 0; itb < 28; itb += 4) {  // bufs cycle 0,1,2,3: LDS addrs loop-invariant
    BODY(itb, 0, 1, 2, 8, 2);
    BODY(itb + 1, 1, 1, 3, 8, 2);
    BODY(itb + 2, 2, 1, 0, 8, 2);
    BODY(itb + 3, 3, 1, 1, 8, 2);
  }
  BODY(28, 0, 1, 2, 8, 2);
  BODY(29, 1, 1, 3, 8, 2);
  BODY(30, 2, 1, 0, 8, 2);  // dummy stage (next bh's K / vw bytes) -> buf0, never read
  BODY(31, 3, 0, 0, 6, 0);
#undef BODY
#undef STAGEP

  __syncthreads();  // all waves done (incl. their dummy-stage drain) before LDS reuse

  // ---- epilogue: cross-wk reduce of O and l, then out = O / l ----
  if (wk == 1) {
    if (l31 == 0) {  // lanes 0 and 32 cover all 32 qrows of this wq-half
#pragma unroll
      for (int g = 0; g < 16; g++) {
        int qrow = 4 * hl + (g & 3) + 8 * (g >> 2);
        *(float*)(smem + 33024 + (wq * 32 + qrow) * 4) = lsacc[g];
      }
    }
#pragma unroll
    for (int wh = 0; wh < 2; wh++) {  // partial O as [w][q] f32 into bufs 0-1
      int vrow = wh * 32 + l31;
#pragma unroll
      for (int m = 0; m < 4; m++) {
        f32x4 part = (f32x4){oacc[wh][4 * m], oacc[wh][4 * m + 1],
                             oacc[wh][4 * m + 2], oacc[wh][4 * m + 3]};
        *(f32x4*)(smem + wq * 8192 + vrow * 128 + SWZ(vrow, hl * 16 + m * 32)) = part;
      }
    }
  }
  __syncthreads();
  if (wk == 0) {
    float linv[16];
#pragma unroll
    for (int g = 0; g < 16; g++) {
      int qrow = 4 * hl + (g & 3) + 8 * (g >> 2);
      float l1 = *(const float*)(smem + 33024 + (wq * 32 + qrow) * 4);
      linv[g] = __builtin_amdgcn_rcpf(lsacc[g] + l1);
    }
#pragma unroll
    for (int wh = 0; wh < 2; wh++) {
      int vrow = wh * 32 + l31;
#pragma unroll
      for (int m = 0; m < 4; m++) {
        f32x4 part = *(const f32x4*)(smem + wq * 8192 + vrow * 128 + SWZ(vrow, hl * 16 + m * 32));
#pragma unroll
        for (int r = 0; r < 4; r++) {
          int g = 4 * m + r;
          int qrow = 4 * hl + r + 8 * m;
          float val = (oacc[wh][g] + part[r]) * linv[g];
          out[((size_t)b * 2048 + qb * 64 + wq * 32 + qrow) * 768 + hh * 64 + wh * 32 + l31] =
              val;
        }
      }
    }
  }
}

// ---------------- launch ----------------
extern "C" void kernel_launch(void* const* d_in, const int* in_sizes, int n_in,
                              void* d_out, int out_size, void* d_ws, size_t ws_size,
                              hipStream_t stream) {
  (void)in_sizes; (void)n_in; (void)out_size; (void)ws_size;
  const float* x  = (const float*)d_in[0];
  const float* Wq = (const float*)d_in[1];
  const float* bq = (const float*)d_in[2];
  const float* Wk = (const float*)d_in[3];
  const float* bk = (const float*)d_in[4];
  const float* Wv = (const float*)d_in[5];
  const float* bv = (const float*)d_in[6];
  const int* mask = (const int*)d_in[7];
  float* out = (float*)d_out;

  char* ws = (char*)d_ws;
  unsigned short* xb = (unsigned short*)(ws);             // 4096x768 bf16   (6291456 B)
  unsigned short* wb = (unsigned short*)(ws + 6291456);   // 3x 768x768 bf16 (3538944 B)
  unsigned short* qw = (unsigned short*)(ws + 9830400);   // (B,H,S,W) bf16
  unsigned short* kw = (unsigned short*)(ws + 16121856);  // (B,H,S,W) bf16
  unsigned short* vw = (unsigned short*)(ws + 22413312);  // (B,H,W,S) bf16

  cvt_all<<<2400, 256, 0, stream>>>(x, Wq, Wk, Wv, xb, wb);
  proj_gemm<<<dim3(32, 18), 256, 0, stream>>>(xb, wb, bq, bk, bv, qw, kw, vw);
  attn_kernel<<<dim3(32, 24), 256, 0, stream>>>(qw, kw, vw, mask, out);
}

// Round 8
// 82.517 us; speedup vs baseline: 1.7847x; 1.7847x over previous
//
#include <hip/hip_runtime.h>
#include <hip/hip_bf16.h>
#include <stdint.h>

// BERT self-attention fwd: B=2, S=2048, D=768, H=12, W=64. f32 in/out, bf16 MFMA inside.
// Stage 1: cvt x,Wq,Wk,Wv -> bf16 (one kernel).
// Stage 2: QKV projection GEMM, BK=32, 3-buf LDS, depth-2 prefetch, 2 barriers/iter.
// Stage 3: flash attention, 32x32 MFMA, no-max softmax, swapped QK^T, in-register P via
//   cvt_pk + permlane32_swap, row-sum via MFMA-with-ones, [16][512B] conflict-free LDS tiles.
//   SOFTWARE-PIPELINED: body = QK(it) || softmax(it-1)+PV(it-1); sc carried in scA/scB
//   (static alternation). 3 bufs, stage depth-1 (one-body cover), 2 barriers/iter.
//   Race ledger: stage(it+1)->buf (it+1)%3; readers K(it)=it%3, V(it-1)=(it-1)%3 distinct;
//   barrier#2(it-1) orders stage(it+1) after all PV(it-2) reads.

typedef __attribute__((ext_vector_type(8))) short bf16x8;    // 8 bf16 = 4 VGPR (MFMA A/B frag)
typedef __attribute__((ext_vector_type(4))) float f32x4;     // 16x16 MFMA C/D frag
typedef __attribute__((ext_vector_type(16))) float f32x16;   // 32x32 MFMA C/D frag
typedef __attribute__((ext_vector_type(8))) unsigned short u16x8;

#define MFMA16(a, b, c) __builtin_amdgcn_mfma_f32_16x16x32_bf16((a), (b), (c), 0, 0, 0)
#define MFMA32(a, b, c) __builtin_amdgcn_mfma_f32_32x32x16_bf16((a), (b), (c), 0, 0, 0)
#define SWZ(row, colb) ((colb) ^ (((row) & 7) << 4))  // 128B-row swizzle (epilogue only)

union U32x4BF {
  unsigned u[4];
  bf16x8 v;
};

__device__ __forceinline__ void gl_lds16(const void* g, void* l) {
  __builtin_amdgcn_global_load_lds(
      (__attribute__((address_space(1))) void*)const_cast<void*>(g),
      (__attribute__((address_space(3))) void*)l, 16, 0, 0);
}

__device__ __forceinline__ unsigned short f2bf(float x) {  // RNE f32->bf16
  unsigned int v = __float_as_uint(x);
  return (unsigned short)((v + 0x7fffu + ((v >> 16) & 1u)) >> 16);
}

// ---------------- Stage 1: f32 -> bf16 convert ----------------
__global__ __launch_bounds__(256) void cvt_all(
    const float* __restrict__ x, const float* __restrict__ wq,
    const float* __restrict__ wk, const float* __restrict__ wv,
    unsigned short* __restrict__ xb, unsigned short* __restrict__ wb) {
  int i = blockIdx.x * 256 + threadIdx.x;  // group-of-8 index; total 614400
  const float* s;
  unsigned short* d;
  int off;
  if (i < 393216)      { s = x;  d = xb;            off = i; }
  else if (i < 466944) { s = wq; d = wb;            off = i - 393216; }
  else if (i < 540672) { s = wk; d = wb + 589824;   off = i - 466944; }
  else                 { s = wv; d = wb + 1179648;  off = i - 540672; }
  const float4* sp = (const float4*)s + (size_t)off * 2;
  float4 a = sp[0], b2 = sp[1];
  u16x8 o;
  o[0] = f2bf(a.x); o[1] = f2bf(a.y); o[2] = f2bf(a.z); o[3] = f2bf(a.w);
  o[4] = f2bf(b2.x); o[5] = f2bf(b2.y); o[6] = f2bf(b2.z); o[7] = f2bf(b2.w);
  *((u16x8*)d + off) = o;
}

// ---------------- Stage 2: fused QKV projection (BK=32, 3-buf, depth-2) ----------------
__global__ __launch_bounds__(256) void proj_gemm(
    const unsigned short* __restrict__ xb, const unsigned short* __restrict__ wb,
    const float* __restrict__ bq, const float* __restrict__ bk, const float* __restrict__ bv,
    unsigned short* __restrict__ qw, unsigned short* __restrict__ kw,
    unsigned short* __restrict__ vw) {
  __shared__ __align__(16) char psmem[49152];  // 3 bufs x (A 8KB | B 8KB)
  const int t = threadIdx.x, lane = t & 63, wave = t >> 6;
  const int lo = lane & 15, hi = lane >> 4;  // hi in 0..3
  const int wr = wave >> 1, wc = wave & 1;   // 2x2 waves, 64x64 each
  const int mbase = blockIdx.x * 128;
  const int wsel = blockIdx.y / 6;
  const int nbase = (blockIdx.y % 6) * 128;
  const char* xc = (const char*)xb;
  const char* wmc = (const char*)(wb + (size_t)wsel * 589824);

  const int pp0 = t * 16, pp1 = t * 16 + 4096;
  const int ar0 = pp0 >> 7, ac0 = (pp0 & 127) ^ ((ar0 & 7) << 4);
  const int am0 = ((ac0 >> 6) << 6) + ar0, ak0 = ac0 & 63;
  const int ar1 = pp1 >> 7, ac1 = (pp1 & 127) ^ ((ar1 & 7) << 4);
  const int am1 = ((ac1 >> 6) << 6) + ar1, ak1 = ac1 & 63;

  const char* xa0 = xc + (size_t)(mbase + am0) * 1536 + ak0;
  const char* xa1 = xc + (size_t)(mbase + am1) * 1536 + ak1;
  const char* wa0 = wmc + (size_t)(nbase + am0) * 1536 + ak0;
  const char* wa1 = wmc + (size_t)(nbase + am1) * 1536 + ak1;

#define PSTAGE(BUF)                              \
  do {                                           \
    char* lb = psmem + (BUF) * 16384;            \
    gl_lds16(xa0, lb + pp0);                     \
    gl_lds16(xa1, lb + pp1);                     \
    gl_lds16(wa0, lb + 8192 + pp0);              \
    gl_lds16(wa1, lb + 8192 + pp1);              \
    xa0 += 64; xa1 += 64; wa0 += 64; wa1 += 64;  \
  } while (0)

  f32x4 acc[4][4];
#pragma unroll
  for (int i = 0; i < 4; i++)
#pragma unroll
    for (int j = 0; j < 4; j++) acc[i][j] = (f32x4){0.f, 0.f, 0.f, 0.f};

  const int axor = (lo & 7) << 4;
  PSTAGE(0);
  PSTAGE(1);
  int cur = 0, sb = 2;
#pragma unroll 1
  for (int it = 0; it < 24; ++it) {
    if (it < 22) {
      PSTAGE(sb);
      asm volatile("s_waitcnt vmcnt(8)" ::: "memory");
    } else if (it == 22) {
      asm volatile("s_waitcnt vmcnt(4)" ::: "memory");
    } else {
      asm volatile("s_waitcnt vmcnt(0)" ::: "memory");
    }
    __builtin_amdgcn_s_barrier();
    const char* lA = psmem + cur * 16384;
    const char* lB = lA + 8192;

    bf16x8 af[4], bf[4];
#pragma unroll
    for (int mf = 0; mf < 4; mf++)
      af[mf] = *(const bf16x8*)(lA + (mf * 16 + lo) * 128 + ((wr * 64 + hi * 16) ^ axor));
#pragma unroll
    for (int nf = 0; nf < 4; nf++)
      bf[nf] = *(const bf16x8*)(lB + (nf * 16 + lo) * 128 + ((wc * 64 + hi * 16) ^ axor));

    __builtin_amdgcn_s_setprio(1);
    if (wsel == 2) {  // V: operand-swapped -> acc holds C^T (rows=n, cols=m)
#pragma unroll
      for (int mf = 0; mf < 4; mf++)
#pragma unroll
        for (int nf = 0; nf < 4; nf++) acc[mf][nf] = MFMA16(bf[nf], af[mf], acc[mf][nf]);
    } else {
#pragma unroll
      for (int mf = 0; mf < 4; mf++)
#pragma unroll
        for (int nf = 0; nf < 4; nf++) acc[mf][nf] = MFMA16(af[mf], bf[nf], acc[mf][nf]);
    }
    __builtin_amdgcn_s_setprio(0);
    __builtin_amdgcn_s_barrier();  // trailing barrier: depth-2 with 3 bufs race-free
    cur = (cur == 2) ? 0 : cur + 1;
    sb = (sb == 2) ? 0 : sb + 1;
  }
#undef PSTAGE

  const float QSCALE = 0.125f * 1.44269504089f;  // fold 1/sqrt(64) * log2(e)
  if (wsel == 2) {
#pragma unroll
    for (int nf = 0; nf < 4; nf++) {
#pragma unroll
      for (int mf = 0; mf < 4; mf++) {
#pragma unroll
        for (int r = 0; r < 4; r++) {
          int n = nbase + wc * 64 + nf * 16 + hi * 4 + r;
          int m = mbase + wr * 64 + mf * 16 + lo;
          int b_ = m >> 11, s = m & 2047;
          int h = n >> 6, wcol = n & 63;
          float val = acc[mf][nf][r] + bv[n];
          vw[(((size_t)b_ * 12 + h) * 64 + wcol) * 2048 + s] = f2bf(val);
        }
      }
    }
  } else {
    const float* bias = (wsel == 0) ? bq : bk;
#pragma unroll
    for (int nf = 0; nf < 4; nf++) {
      int n = nbase + wc * 64 + nf * 16 + lo;
      float bv_ = bias[n];
      int h = n >> 6, wcol = n & 63;
#pragma unroll
      for (int mf = 0; mf < 4; mf++) {
#pragma unroll
        for (int r = 0; r < 4; r++) {
          int m = mbase + wr * 64 + mf * 16 + hi * 4 + r;
          int b_ = m >> 11, s = m & 2047;
          float val = acc[mf][nf][r] + bv_;
          size_t bhh = (size_t)b_ * 12 + h;
          if (wsel == 0)
            qw[(bhh * 2048 + s) * 64 + wcol] = f2bf(val * QSCALE);
          else
            kw[(bhh * 2048 + s) * 64 + wcol] = f2bf(val);
        }
      }
    }
  }
}

// ---------------- Stage 3: flash attention (software-pipelined) ----------------
// grid (32, 24), block 256 = 4 waves (wq q-half x wk key-half). KT=64 keys/iter, 32 iters.
// K tile [16][512B]: key k, dbyte d: (k&15)*512 + (k>>4)*128 + (d ^ ((k&7)<<4)); V same on w.
// Body(it): STAGE(it+1) -> vmcnt(4) -> barrier -> QK(it)->scCUR  ||  softmax(it-1 from
// scPREV) + PV(it-1) -> barrier.  QK result never waited on (consumed next iter).
__global__ __launch_bounds__(256) void attn_kernel(
    const unsigned short* __restrict__ qw, const unsigned short* __restrict__ kw,
    const unsigned short* __restrict__ vw, const int* __restrict__ mask,
    float* __restrict__ out) {
  // [0,49152): 3 bufs x (K 8KB | V 8KB) | [49152,49408) ballots | [49408,49664) lsum f32[64]
  __shared__ __align__(16) char smem[49664];
  const int t = threadIdx.x, lane = t & 63, wave = t >> 6;
  const int wq = wave >> 1, wk = wave & 1;
  const int l31 = lane & 31, hl = lane >> 5;
  const int qb = blockIdx.x, bh = blockIdx.y;
  const int b = bh / 12, hh = bh - b * 12;

  // bit-pack mask: thread t packs keys [t*8, t*8+8) -> ballot bytes
  {
    const int* mb = mask + (size_t)b * 2048 + t * 8;
    int4 a0 = *(const int4*)mb;
    int4 a1 = *(const int4*)(mb + 4);
    unsigned by = (unsigned)(a0.x != 0) | ((unsigned)(a0.y != 0) << 1) |
                  ((unsigned)(a0.z != 0) << 2) | ((unsigned)(a0.w != 0) << 3) |
                  ((unsigned)(a1.x != 0) << 4) | ((unsigned)(a1.y != 0) << 5) |
                  ((unsigned)(a1.z != 0) << 6) | ((unsigned)(a1.w != 0) << 7);
    smem[49152 + t] = (char)by;
  }

  // Q B-frags in registers: lane holds Q[q = l31 of wq-half][d = 16s + 8hl + j]
  bf16x8 qv[4];
  {
    int qrow = qb * 64 + wq * 32 + l31;
    const char* qp = (const char*)qw + ((size_t)bh * 2048 + qrow) * 128 + hl * 16;
#pragma unroll
    for (int s = 0; s < 4; s++) qv[s] = *(const bf16x8*)(qp + s * 32);
  }

  // staging maps: linear p -> (key|w, byte-within-row), pre-swizzled source
  const int p0 = t * 16, p1 = t * 16 + 4096;
  const int r0 = p0 >> 9, c0 = (p0 >> 7) & 3, o0 = (p0 & 127) ^ ((r0 & 7) << 4);
  const int r1 = p1 >> 9, c1 = (p1 >> 7) & 3, o1 = (p1 & 127) ^ ((r1 & 7) << 4);

  const char* kp0 = (const char*)kw + (size_t)bh * 262144 + (c0 * 16 + r0) * 128 + o0;
  const char* kp1 = (const char*)kw + (size_t)bh * 262144 + (c1 * 16 + r1) * 128 + o1;
  const char* vp0 = (const char*)vw + (size_t)bh * 262144 + (size_t)(c0 * 16 + r0) * 4096 + o0;
  const char* vp1 = (const char*)vw + (size_t)bh * 262144 + (size_t)(c1 * 16 + r1) * 4096 + o1;

#define STAGEP(BUF_)                                  \
  do {                                                \
    char* kb_ = smem + (BUF_) * 16384;                \
    gl_lds16(kp0, kb_ + p0);                          \
    gl_lds16(kp1, kb_ + p1);                          \
    gl_lds16(vp0, kb_ + 8192 + p0);                   \
    gl_lds16(vp1, kb_ + 8192 + p1);                   \
    kp0 += 8192; kp1 += 8192; vp0 += 128; vp1 += 128; \
  } while (0)

  f32x16 oacc[2], lsacc, scA, scB;
#pragma unroll
  for (int wh = 0; wh < 2; wh++)
#pragma unroll
    for (int g = 0; g < 16; g++) oacc[wh][g] = 0.f;
#pragma unroll
  for (int g = 0; g < 16; g++) lsacc[g] = 0.f;
  U32x4BF onesv;
  onesv.u[0] = onesv.u[1] = onesv.u[2] = onesv.u[3] = 0x3F803F80u;  // 8x bf16 1.0

  const int kbl = (l31 & 15) * 512 + (wk * 2 + (l31 >> 4)) * 128;  // K frag row part
  const int rxor = (l31 & 7) << 4;
  const int hl16 = hl * 16;

// softmax on SCP_ (scores of tile ITP_) + lsacc + PV from V buf BPV_
#define SMPV(ITP_, BPV_, SCP_)                                                          \
  {                                                                                     \
    unsigned long long bal_ = *(const unsigned long long*)(smem + 49152 + (ITP_) * 8);  \
    if (bal_ != ~0ull) {                                                                \
      _Pragma("unroll") for (int g = 0; g < 16; g++) {                                  \
        int key_ = wk * 32 + 4 * hl + (g & 3) + 8 * (g >> 2);                           \
        if (!((bal_ >> key_) & 1)) SCP_[g] = -30000.f;                                  \
      }                                                                                 \
    }                                                                                   \
    _Pragma("unroll") for (int g = 0; g < 16; g++) {                                    \
      float t_;                                                                         \
      asm("v_exp_f32 %0, %1" : "=v"(t_) : "v"(SCP_[g]));                                \
      SCP_[g] = t_;                                                                     \
    }                                                                                   \
    unsigned pk_[4][2];                                                                 \
    _Pragma("unroll") for (int m = 0; m < 4; m++) {                                     \
      asm("v_cvt_pk_bf16_f32 %0, %1, %2"                                                \
          : "=v"(pk_[m][0]) : "v"(SCP_[4 * m]), "v"(SCP_[4 * m + 1]));                  \
      asm("v_cvt_pk_bf16_f32 %0, %1, %2"                                                \
          : "=v"(pk_[m][1]) : "v"(SCP_[4 * m + 2]), "v"(SCP_[4 * m + 3]));              \
    }                                                                                   \
    U32x4BF apv_[2];                                                                    \
    _Pragma("unroll") for (int sp = 0; sp < 2; sp++)                                    \
        _Pragma("unroll") for (int cp = 0; cp < 2; cp++) {                              \
      unsigned xx_ = pk_[2 * sp][cp], yy_ = pk_[2 * sp + 1][cp];                        \
      asm("v_permlane32_swap_b32 %0, %1" : "+v"(xx_), "+v"(yy_));                       \
      apv_[sp].u[cp] = xx_;                                                             \
      apv_[sp].u[2 + cp] = yy_;                                                         \
    }                                                                                   \
    __builtin_amdgcn_s_setprio(1);                                                      \
    lsacc = MFMA32(apv_[0].v, onesv.v, lsacc);                                          \
    lsacc = MFMA32(apv_[1].v, onesv.v, lsacc);                                          \
    const char* lVc_ = smem + (BPV_) * 16384 + 8192;                                    \
    _Pragma("unroll") for (int wh = 0; wh < 2; wh++) {                                  \
      int vbl_ = (l31 & 15) * 512 + (wh * 2 + (l31 >> 4)) * 128;                        \
      _Pragma("unroll") for (int sp = 0; sp < 2; sp++) {                                \
        bf16x8 vf_ = *(const bf16x8*)(lVc_ + vbl_ + ((wk * 64 + sp * 32 + hl16) ^ rxor)); \
        oacc[wh] = MFMA32(apv_[sp].v, vf_, oacc[wh]);                                   \
      }                                                                                 \
    }                                                                                   \
    __builtin_amdgcn_s_setprio(0);                                                      \
  }

// pipelined body: stage(it+1) -> vmcnt -> barrier -> QK(it)->SCQ_ ; SMPV(it-1) ; barrier
#define BODY(IT_, BQK_, SBUF_, BPV_, DOSTG_, VMW_, SCQ_, SCP_)                \
  {                                                                           \
    if (DOSTG_) STAGEP(SBUF_);                                                \
    asm volatile("s_waitcnt vmcnt(" #VMW_ ")" ::: "memory");                  \
    __builtin_amdgcn_s_barrier();                                             \
    const char* lKc_ = smem + (BQK_) * 16384;                                 \
    _Pragma("unroll") for (int g = 0; g < 16; g++) SCQ_[g] = 0.f;             \
    __builtin_amdgcn_s_setprio(1);                                            \
    _Pragma("unroll") for (int s = 0; s < 4; s++) {                           \
      bf16x8 kf_ = *(const bf16x8*)(lKc_ + kbl + ((s * 32 + hl16) ^ rxor));   \
      SCQ_ = MFMA32(kf_, qv[s], SCQ_);                                        \
    }                                                                         \
    __builtin_amdgcn_s_setprio(0);                                            \
    SMPV((IT_) - 1, BPV_, SCP_);                                              \
    __builtin_amdgcn_s_barrier();                                             \
  }

  // prologue: stage tiles 0,1; drain stage(0); publish ballots+LDS; QK(0)->scA
  STAGEP(0);
  STAGEP(1);
  asm volatile("s_waitcnt vmcnt(4) lgkmcnt(0)" ::: "memory");
  __builtin_amdgcn_s_barrier();
  {
    const char* lKc_ = smem;
#pragma unroll
    for (int g = 0; g < 16; g++) scA[g] = 0.f;
#pragma unroll
    for (int s = 0; s < 4; s++) {
      bf16x8 kf_ = *(const bf16x8*)(lKc_ + kbl + ((s * 32 + hl16) ^ rxor));
      scA = MFMA32(kf_, qv[s], scA);
    }
  }

#pragma unroll 1
  for (int itb = 1; itb < 31; itb += 6) {  // it = itb..itb+5; itb%3==1 -> static buf indices
    BODY(itb + 0, 1, 2, 0, 1, 4, scB, scA);
    BODY(itb + 1, 2, 0, 1, 1, 4, scA, scB);
    BODY(itb + 2, 0, 1, 2, 1, 4, scB, scA);
    BODY(itb + 3, 1, 2, 0, 1, 4, scA, scB);
    BODY(itb + 4, 2, 0, 1, 1, 4, scB, scA);
    BODY(itb + 5, 0, 1, 2, 1, 4, scA, scB);
  }
  BODY(31, 1, 0, 0, 0, 0, scB, scA);  // no stage; drain stage(31)
  SMPV(31, 1, scB);                   // epilogue finish of last tile
#undef BODY
#undef SMPV
#undef STAGEP

  // ---- epilogue: cross-wk reduce of O and l, then out = O / l ----
  if (wk == 1) {
    if (l31 == 0) {  // lanes 0 and 32 cover all 32 qrows of this wq-half
#pragma unroll
      for (int g = 0; g < 16; g++) {
        int qrow = 4 * hl + (g & 3) + 8 * (g >> 2);
        *(float*)(smem + 49408 + (wq * 32 + qrow) * 4) = lsacc[g];
      }
    }
#pragma unroll
    for (int wh = 0; wh < 2; wh++) {  // partial O as [w][q] f32 into buf0 region
      int vrow = wh * 32 + l31;
#pragma unroll
      for (int m = 0; m < 4; m++) {
        f32x4 part = (f32x4){oacc[wh][4 * m], oacc[wh][4 * m + 1],
                             oacc[wh][4 * m + 2], oacc[wh][4 * m + 3]};
        *(f32x4*)(smem + wq * 8192 + vrow * 128 + SWZ(vrow, hl * 16 + m * 32)) = part;
      }
    }
  }
  __syncthreads();
  if (wk == 0) {
    float linv[16];
#pragma unroll
    for (int g = 0; g < 16; g++) {
      int qrow = 4 * hl + (g & 3) + 8 * (g >> 2);
      float l1 = *(const float*)(smem + 49408 + (wq * 32 + qrow) * 4);
      linv[g] = __builtin_amdgcn_rcpf(lsacc[g] + l1);
    }
#pragma unroll
    for (int wh = 0; wh < 2; wh++) {
      int vrow = wh * 32 + l31;
#pragma unroll
      for (int m = 0; m < 4; m++) {
        f32x4 part = *(const f32x4*)(smem + wq * 8192 + vrow * 128 + SWZ(vrow, hl * 16 + m * 32));
#pragma unroll
        for (int r = 0; r < 4; r++) {
          int g = 4 * m + r;
          int qrow = 4 * hl + r + 8 * m;
          float val = (oacc[wh][g] + part[r]) * linv[g];
          out[((size_t)b * 2048 + qb * 64 + wq * 32 + qrow) * 768 + hh * 64 + wh * 32 + l31] =
              val;
        }
      }
    }
  }
}

// ---------------- launch ----------------
extern "C" void kernel_launch(void* const* d_in, const int* in_sizes, int n_in,
                              void* d_out, int out_size, void* d_ws, size_t ws_size,
                              hipStream_t stream) {
  (void)in_sizes; (void)n_in; (void)out_size; (void)ws_size;
  const float* x  = (const float*)d_in[0];
  const float* Wq = (const float*)d_in[1];
  const float* bq = (const float*)d_in[2];
  const float* Wk = (const float*)d_in[3];
  const float* bk = (const float*)d_in[4];
  const float* Wv = (const float*)d_in[5];
  const float* bv = (const float*)d_in[6];
  const int* mask = (const int*)d_in[7];
  float* out = (float*)d_out;

  char* ws = (char*)d_ws;
  unsigned short* xb = (unsigned short*)(ws);             // 4096x768 bf16   (6291456 B)
  unsigned short* wb = (unsigned short*)(ws + 6291456);   // 3x 768x768 bf16 (3538944 B)
  unsigned short* qw = (unsigned short*)(ws + 9830400);   // (B,H,S,W) bf16
  unsigned short* kw = (unsigned short*)(ws + 16121856);  // (B,H,S,W) bf16
  unsigned short* vw = (unsigned short*)(ws + 22413312);  // (B,H,W,S) bf16

  cvt_all<<<2400, 256, 0, stream>>>(x, Wq, Wk, Wv, xb, wb);
  proj_gemm<<<dim3(32, 18), 256, 0, stream>>>(xb, wb, bq, bk, bv, qw, kw, vw);
  attn_kernel<<<dim3(32, 24), 256, 0, stream>>>(qw, kw, vw, mask, out);
}